// Round 10
// baseline (236.231 us; speedup 1.0000x reference)
//
#include <hip/hip_runtime.h>
#include <stdint.h>

typedef __attribute__((ext_vector_type(8))) short bf16x8;
typedef __attribute__((ext_vector_type(4))) float f32x4;
typedef __attribute__((ext_vector_type(16))) float f32x16;

#if __has_builtin(__builtin_amdgcn_exp2f)
#define EXP2F(x) __builtin_amdgcn_exp2f(x)
#else
#define EXP2F(x) exp2f(x)
#endif

__device__ __forceinline__ short f2bf(float f) {
    union { float f; uint32_t u; } c; c.f = f;
    return (short)((c.u + 0x7fffu + ((c.u >> 16) & 1u)) >> 16);
}

// ---- prep: Wt3 [32 ksteps][6 n32][32 col][2 kh][8 k] bf16 (dense 1KB B-frags) + bcat[192]
__global__ void prep_kernel(const float* __restrict__ Wk, const float* __restrict__ bk,
                            const float* __restrict__ Wq, const float* __restrict__ bq,
                            const float* __restrict__ Wv, const float* __restrict__ bv,
                            short* __restrict__ Wt3, float* __restrict__ bcat) {
    const int col = blockIdx.x;  // 0..191 (0-63=K, 64-127=Q, 128-191=V)
    const float* W; const float* bb; int c0;
    if (col < 64)       { W = Wk; bb = bk; c0 = col; }
    else if (col < 128) { W = Wq; bb = bq; c0 = col - 64; }
    else                { W = Wv; bb = bv; c0 = col - 128; }
    const int n32 = col >> 5, cc = col & 31;
    for (int c = threadIdx.x; c < 512; c += blockDim.x) {
        const int kstep = c >> 4, khh = (c >> 3) & 1, i = c & 7;
        Wt3[(size_t)(kstep * 6 + n32) * 512 + cc * 16 + khh * 8 + i] = f2bf(W[(size_t)c * 64 + c0]);
    }
    if (threadIdx.x == 0) bcat[col] = bb[c0];
}

// ---- fused per-batch kernel: all-VGPR QKV GEMM -> LDS -> causal attention ----
// grid 256 (1 block/batch), 1024 thr = 16 waves. Wave w = (m32 = w>>1, ng = w&1):
// 3 output 32x32 tiles (n32 = {ng, 2+ng, 4+ng} = K/Q/V halves) over its 32 rows.
// Phase 1: ZERO LDS, ZERO global_load_lds, ZERO barriers — x A-frags and W B-frags
// load direct to VGPR (dense, line-efficient); compiler pipelines the unrolled loop.
// (R9 A/B: only the x path changed — tests the LDS-DMA-engine serialization theory.)
// Phase 2: R7/R9-verified all-LDS attention, q-tile = wave.
// LDS 118784 B (phase 2 only): Ks@0 32K | Qs@32768 32K | Vts@65536 32K | Ps@98304 20K.
#define PSTR 40

__global__ __launch_bounds__(1024, 4) void fused_kernel(
    const float* __restrict__ x, const short* __restrict__ Wt3,
    const float* __restrict__ bcat, float* __restrict__ out) {
    extern __shared__ __align__(16) char smem[];

    const int tid = threadIdx.x;
    const int wave = tid >> 6, lane = tid & 63;
    const int quad = lane >> 4, l16 = lane & 15;
    const int l32 = lane & 31, kh = lane >> 5;
    const int b = blockIdx.x;
    const int m32 = wave >> 1, ng = wave & 1;

    // ================= phase 1: QKV projection (no LDS, no barriers) =================
    f32x16 acc[3];
#pragma unroll
    for (int t = 0; t < 3; t++)
#pragma unroll
        for (int i = 0; i < 16; i++) acc[t][i] = 0.f;

    // lane's A-stream: row = m32*32 + l32; k = kc*32 + ks*16 + kh*8 + i (8 contiguous fp32)
    const float* xrow = x + ((size_t)b * 256 + m32 * 32 + l32) * 512 + kh * 8;

#pragma unroll
    for (int kc = 0; kc < 16; kc++) {
        // W B-frags: 6 dense 1KB loads (L1/L2-hot, shared addrs across waves)
        bf16x8 wf[2][3];
#pragma unroll
        for (int ks = 0; ks < 2; ks++)
#pragma unroll
            for (int t = 0; t < 3; t++) {
                const int n32 = t * 2 + ng;
                wf[ks][t] = *(const bf16x8*)&Wt3[(size_t)((kc * 2 + ks) * 6 + n32) * 512 +
                                                 l32 * 16 + kh * 8];
            }
        // A frags direct from global (dense 64B/row segments, 2x f32x4 per ks)
        bf16x8 a[2];
#pragma unroll
        for (int ks = 0; ks < 2; ks++) {
            const float* ap = xrow + kc * 32 + ks * 16;
            f32x4 u0 = *(const f32x4*)ap;
            f32x4 u1 = *(const f32x4*)(ap + 4);
#pragma unroll
            for (int i = 0; i < 4; i++) { a[ks][i] = f2bf(u0[i]); a[ks][4 + i] = f2bf(u1[i]); }
        }
#pragma unroll
        for (int ks = 0; ks < 2; ks++)
#pragma unroll
            for (int t = 0; t < 3; t++)
                acc[t] = __builtin_amdgcn_mfma_f32_32x32x16_bf16(a[ks], wf[ks][t], acc[t], 0, 0, 0);
    }

    // ---- epilogue: 32x32 C-layout (col=lane&31, row=(reg&3)+8*(reg>>2)+4*kh) ----
    short* Ks  = (short*)smem;               // [256 rows][64 h], slot^(row&7)
    short* Qs  = (short*)(smem + 32768);     // [256 rows][64 h], slot^(row&7)
    short* Vts = (short*)(smem + 65536);     // [64 h][256 s],   slot^(h&7)
    short* Ps  = (short*)(smem + 98304);     // per-wave 16 x PSTR
#pragma unroll
    for (int t = 0; t < 3; t++) {
        const int h = ng * 32 + l32;
        const float bias = bcat[t * 64 + h];
#pragma unroll
        for (int reg = 0; reg < 16; reg++) {
            const int row = m32 * 32 + (reg & 3) + 8 * (reg >> 2) + 4 * kh;
            const short v = f2bf(acc[t][reg] + bias);
            if (t == 0)      Ks[row * 64 + (((h >> 3) ^ (row & 7)) << 3) + (h & 7)] = v;
            else if (t == 1) Qs[row * 64 + (((h >> 3) ^ (row & 7)) << 3) + (h & 7)] = v;
            else             Vts[h * 256 + (((row >> 3) ^ (h & 7)) << 3) + (row & 7)] = v;
        }
    }
    __syncthreads();   // the only block-wide barrier: K/Q/V visible

    // ================= phase 2: causal attention, all-LDS (R7/R9-verified) =================
    const float sc2 = 0.125f * 1.44269504088896340736f;  // 1/sqrt(64) * log2(e)
    short* myP = Ps + wave * (16 * PSTR);
    const int tq = wave;

    const int qrow = tq * 16 + l16;
    const int sw = l16 & 7;
    bf16x8 qf0 = *(const bf16x8*)&Qs[qrow * 64 + ((quad ^ sw) << 3)];
    bf16x8 qf1 = *(const bf16x8*)&Qs[qrow * 64 + (((4 + quad) ^ sw) << 3)];

    f32x4 St[16];
#pragma unroll
    for (int i = 0; i < 16; i++) St[i] = (f32x4){0.f, 0.f, 0.f, 0.f};
#pragma unroll
    for (int nt = 0; nt < 16; nt++) if (nt <= tq) {
        const int krow = nt * 16 + l16;
        bf16x8 kf0 = *(const bf16x8*)&Ks[krow * 64 + ((quad ^ (krow & 7)) << 3)];
        bf16x8 kf1 = *(const bf16x8*)&Ks[krow * 64 + (((4 + quad) ^ (krow & 7)) << 3)];
        St[nt] = __builtin_amdgcn_mfma_f32_16x16x32_bf16(qf0, kf0, St[nt], 0, 0, 0);
        St[nt] = __builtin_amdgcn_mfma_f32_16x16x32_bf16(qf1, kf1, St[nt], 0, 0, 0);
    }

    // mask + base-2 softmax; C-layout rows = quad*4+r, col = l16
    const int rowq = tq * 16 + quad * 4;
    float mx[4], ls[4];
#pragma unroll
    for (int r = 0; r < 4; r++) mx[r] = -3.0e38f;
#pragma unroll
    for (int nt = 0; nt < 16; nt++) if (nt <= tq) {
        const int cs = nt * 16 + l16;
#pragma unroll
        for (int r = 0; r < 4; r++) {
            float s = (cs <= rowq + r) ? St[nt][r] * sc2 : -3.0e38f;
            St[nt][r] = s;
            mx[r] = fmaxf(mx[r], s);
        }
    }
#pragma unroll
    for (int d = 1; d < 16; d <<= 1)
#pragma unroll
        for (int r = 0; r < 4; r++)
            mx[r] = fmaxf(mx[r], __shfl_xor(mx[r], d, 64));
#pragma unroll
    for (int r = 0; r < 4; r++) ls[r] = 0.f;
#pragma unroll
    for (int nt = 0; nt < 16; nt++) if (nt <= tq) {
#pragma unroll
        for (int r = 0; r < 4; r++) {
            float p = EXP2F(St[nt][r] - mx[r]);
            St[nt][r] = p;                 // St[nt>tq] stays 0 == correct P
            ls[r] += p;
        }
    }
#pragma unroll
    for (int d = 1; d < 16; d <<= 1)
#pragma unroll
        for (int r = 0; r < 4; r++)
            ls[r] += __shfl_xor(ls[r], d, 64);

    // O = P V over 32-s chunks; P via wave-local LDS C->A roundtrip
    f32x4 O[4];
#pragma unroll
    for (int i = 0; i < 4; i++) O[i] = (f32x4){0.f, 0.f, 0.f, 0.f};
    const int nch = (tq + 2) >> 1;         // ceil((tq+1)/2), wave-uniform
#pragma unroll
    for (int c2 = 0; c2 < 8; c2++) if (c2 < nch) {
#pragma unroll
        for (int t2i = 0; t2i < 2; t2i++) {
            const int nt = c2 * 2 + t2i;   // St[nt]=0 beyond diagonal => P=0
#pragma unroll
            for (int r = 0; r < 4; r++)
                myP[(quad * 4 + r) * PSTR + t2i * 16 + l16] = f2bf(St[nt][r]);
        }
        bf16x8 pf = *(const bf16x8*)&myP[l16 * PSTR + quad * 8];
#pragma unroll
        for (int ht = 0; ht < 4; ht++) {
            const int h = ht * 16 + l16;
            bf16x8 vf = *(const bf16x8*)&Vts[h * 256 + (((c2 * 4 + quad) ^ (h & 7)) << 3)];
            O[ht] = __builtin_amdgcn_mfma_f32_16x16x32_bf16(pf, vf, O[ht], 0, 0, 0);
        }
    }

    float rls[4];
#pragma unroll
    for (int r = 0; r < 4; r++) rls[r] = 1.0f / ls[r];
#pragma unroll
    for (int ht = 0; ht < 4; ht++)
#pragma unroll
        for (int r = 0; r < 4; r++)
            out[((size_t)b * 256 + rowq + r) * 64 + ht * 16 + l16] = O[ht][r] * rls[r];
}

extern "C" void kernel_launch(void* const* d_in, const int* in_sizes, int n_in,
                              void* d_out, int out_size, void* d_ws, size_t ws_size,
                              hipStream_t stream) {
    const float* x  = (const float*)d_in[0];
    const float* Wk = (const float*)d_in[1];
    const float* bk = (const float*)d_in[2];
    const float* Wq = (const float*)d_in[3];
    const float* bq = (const float*)d_in[4];
    const float* Wv = (const float*)d_in[5];
    const float* bv = (const float*)d_in[6];
    float* out = (float*)d_out;

    char* ws = (char*)d_ws;
    short* Wt3  = (short*)(ws);             // 196608 B (kstep-major dense-frag layout)
    float* bcat = (float*)(ws + 196608);    // 768 B

    const int smem_bytes = 118784;          // phase-2 LDS only; >64KB -> dynamic + attribute
    (void)hipFuncSetAttribute((const void*)fused_kernel,
                              hipFuncAttributeMaxDynamicSharedMemorySize, smem_bytes);

    prep_kernel<<<192, 256, 0, stream>>>(Wk, bk, Wq, bq, Wv, bv, Wt3, bcat);
    fused_kernel<<<256, 1024, smem_bytes, stream>>>(x, Wt3, bcat, out);
}